// Round 8
// baseline (118.699 us; speedup 1.0000x reference)
//
#include <hip/hip_runtime.h>
#include <hip/hip_cooperative_groups.h>

namespace cg = cooperative_groups;

#define NVAR   576
#define NROW   144
#define DEG    15
#define NITER  3
#define NWORD  9                 // 576 bits = 9 x 64-bit words per row
#define NWTOT  (NROW * NWORD)    // 1296 bitmask words
#define NBATCH 256
#define NT     192               // 3 waves; t<144 owns a row in decode
#define GWAVES (NBATCH * (NT / 64))   // 768 waves in grid

// One cooperative kernel, 256 blocks x 192 threads (1 block/CU -> co-resident).
// Phase A: grid-wide H -> bitmask-word build; H (331 KB) is read ONCE across
//   the grid (each wave handles <=2 independent ballot words) — avoids both
//   the extra kernel node (R5) and the 256x-replicated H read (R6, 26+ us).
// grid.sync() (device-scope fence) makes bits visible to all blocks.
// Phase B: byte-identical R5 decode: thread t<144 owns row t in registers
//   (cols via ffs from L2-hot bits, M, E, r@cols); LDS holds rs + ping-pong
//   column accumulators; 2 block barriers per iteration; LDS atomic scatter.
__launch_bounds__(NT, 1)
__global__ void ldpc_coop_kernel(const float* __restrict__ r,
                                 const float* __restrict__ H,
                                 const float* __restrict__ alpha,
                                 const float* __restrict__ beta,
                                 unsigned long long* __restrict__ bits,
                                 float* __restrict__ out) {
    __shared__ float rs[NVAR];
    __shared__ float sA[NVAR];         // ping-pong column accumulators
    __shared__ float sB[NVAR];
    __shared__ short colsh[NROW * 16]; // row stride padded to 16 shorts

    const int b    = blockIdx.x;
    const int t    = threadIdx.x;
    const int wv   = t >> 6;           // wave id 0..2
    const int lane = t & 63;

    // ---- Phase A: bits build, H read once grid-wide ----
    {
        int wg = b * 3 + wv;           // global wave id 0..767
        float h0 = H[wg * 64 + lane];  // coalesced 256B per wave
        unsigned long long m0 = __ballot(h0 != 0.0f);
        if (lane == 0) bits[wg] = m0;
        int w2 = wg + GWAVES;          // second word for waves 0..527
        if (w2 < NWTOT) {
            float h1 = H[w2 * 64 + lane];
            unsigned long long m1 = __ballot(h1 != 0.0f);
            if (lane == 0) bits[w2] = m1;
        }
    }

    // Overlap: stage r + zero first accumulator + hoist alpha/beta.
    #pragma unroll
    for (int k = 0; k < 3; ++k) {
        int n = t + k * NT;
        rs[n] = r[b * NVAR + n];
        sA[n] = 0.0f;
    }
    float alr[NITER], ber[NITER];
    #pragma unroll
    for (int i = 0; i < NITER; ++i) { alr[i] = alpha[i]; ber[i] = beta[i]; }

    cg::this_grid().sync();            // bits visible device-wide

    // ---- Phase B: decode (proven R5 structure) ----
    // Extract this row's 15 column indices from its 72B bitmask (L2-hot,
    // ascending order -> matches top_k lowest-index tie-breaking).
    if (t < NROW) {
        unsigned long long w[NWORD];
        #pragma unroll
        for (int i = 0; i < NWORD; ++i) w[i] = bits[t * NWORD + i];
        int k = 0;
        #pragma unroll
        for (int i = 0; i < NWORD; ++i) {
            unsigned long long bw = w[i];
            while (bw) {
                int p = __ffsll((long long)bw) - 1;
                bw &= bw - 1;
                colsh[t * 16 + k] = (short)(i * 64 + p);
                ++k;
            }
        }
    }
    __syncthreads();

    int   ci[DEG];
    float Mv[DEG], Ev[DEG], rc[DEG];
    if (t < NROW) {
        #pragma unroll
        for (int j = 0; j < DEG; ++j) ci[j] = (int)colsh[t * 16 + j];
        #pragma unroll
        for (int j = 0; j < DEG; ++j) { rc[j] = rs[ci[j]]; Mv[j] = rc[j]; }
    }

    #pragma unroll
    for (int it = 0; it < NITER; ++it) {
        float* sum = (it & 1) ? sB : sA;   // scatter target (pre-zeroed)
        float* nxt = (it & 1) ? sA : sB;   // zeroed this iter for next scatter

        if (t < NROW) {
            // In-register min1/min2/argmin/sign-parity reduce over 15 edges.
            float m1 = INFINITY, m2 = INFINITY, sg = 1.0f;
            int j1 = 0;
            #pragma unroll
            for (int j = 0; j < DEG; ++j) {
                float v = Mv[j];
                float a = fabsf(v);
                float s = (v > 0.0f) ? 1.0f : ((v < 0.0f) ? -1.0f : 0.0f);
                sg *= s;
                if (a < m1) { m2 = m1; m1 = a; j1 = j; }
                else if (a < m2) { m2 = a; }
            }
            // E values + column scatter (E stays in registers).
            #pragma unroll
            for (int j = 0; j < DEG; ++j) {
                float v = Mv[j];
                float s = (v > 0.0f) ? 1.0f : ((v < 0.0f) ? -1.0f : 0.0f);
                float eabs = (j == j1) ? m2 : m1;
                float e = alr[it] * sg * s * fmaxf(0.0f, eabs - ber[it]);
                Ev[j] = e;
                atomicAdd(&sum[ci[j]], e);
            }
        }
        __syncthreads();   // drain scatter

        if (it == NITER - 1) {
            #pragma unroll
            for (int k = 0; k < 3; ++k) {
                int n = t + k * NT;
                out[b * NVAR + n] = rs[n] + sum[n];
            }
        } else {
            // Zero the other buffer for the next iteration (disjoint from sum).
            #pragma unroll
            for (int k = 0; k < 3; ++k) nxt[t + k * NT] = 0.0f;
            // In-register M update: M = r + sumE - E at this row's columns.
            if (t < NROW) {
                #pragma unroll
                for (int j = 0; j < DEG; ++j)
                    Mv[j] = rc[j] + sum[ci[j]] - Ev[j];
            }
            __syncthreads();
        }
    }
}

extern "C" void kernel_launch(void* const* d_in, const int* in_sizes, int n_in,
                              void* d_out, int out_size, void* d_ws, size_t ws_size,
                              hipStream_t stream) {
    const float* r     = (const float*)d_in[0];
    const float* H     = (const float*)d_in[1];
    const float* alpha = (const float*)d_in[2];
    const float* beta  = (const float*)d_in[3];
    float* out = (float*)d_out;
    unsigned long long* bits = (unsigned long long*)d_ws;  // 1296*8 B scratch

    void* args[] = {(void*)&r, (void*)&H, (void*)&alpha, (void*)&beta,
                    (void*)&bits, (void*)&out};
    hipLaunchCooperativeKernel((void*)ldpc_coop_kernel,
                               dim3(NBATCH), dim3(NT), args, 0, stream);
}

// Round 9
// 106.972 us; speedup vs baseline: 1.1096x; 1.1096x over previous
//
#include <hip/hip_runtime.h>

#define NVAR   576
#define NROW   144
#define DEG    15
#define NITER  3
#define NWORD  9                 // 576 bits = 9 x 64-bit words per row
#define NWTOT  (NROW * NWORD)    // 1296 bitmask words
#define NBATCH 256
#define NT     192               // decode block: 3 waves; t<144 owns a row

// K1: H -> per-row bitmask words, stored TRANSPOSED: bitsT[w*144 + row].
// One wave per word; chain-free (1 coalesced 256B load + ballot + 8B store).
// Transposed layout makes the decode's per-row word reads lane-consecutive.
__global__ void build_bits_kernel(const float* __restrict__ H,
                                  unsigned long long* __restrict__ bitsT) {
    int gid  = blockIdx.x * blockDim.x + threadIdx.x;
    int wid  = gid >> 6;          // 0..1295 = row*9 + w
    int lane = gid & 63;
    if (wid >= NWTOT) return;
    float h = H[wid * 64 + lane];
    unsigned long long m = __ballot(h != 0.0f);
    int row = wid / NWORD, w = wid - row * NWORD;
    if (lane == 0) bitsT[w * NROW + row] = m;
}

// K2: decode (R5 row-register structure + coalesced early bits prefetch).
// Launched 3x this round purely to measure true per-launch cost (idempotent:
// same inputs -> same d_out). Thread t<144 owns row t in registers; LDS holds
// rs + ping-pong column accumulators; 2 barriers/iter; LDS atomic scatter.
__launch_bounds__(NT, 1)
__global__ void ldpc_decode_kernel(const float* __restrict__ r,
                                   const unsigned long long* __restrict__ bitsT,
                                   const float* __restrict__ alpha,
                                   const float* __restrict__ beta,
                                   float* __restrict__ out) {
    __shared__ float rs[NVAR];
    __shared__ float sA[NVAR];         // ping-pong column accumulators
    __shared__ float sB[NVAR];
    __shared__ short colsh[NROW * 16]; // row stride padded to 16 shorts

    const int b = blockIdx.x;
    const int t = threadIdx.x;

    // Prefetch this row's 9 bitmask words FIRST (coalesced: lane-consecutive
    // 8B in the transposed layout) so their latency hides under r staging.
    unsigned long long w[NWORD];
    if (t < NROW) {
        #pragma unroll
        for (int i = 0; i < NWORD; ++i) w[i] = bitsT[i * NROW + t];
    }

    float alr[NITER], ber[NITER];
    #pragma unroll
    for (int i = 0; i < NITER; ++i) { alr[i] = alpha[i]; ber[i] = beta[i]; }

    // Stage r (coalesced) and zero the first accumulator.
    #pragma unroll
    for (int k = 0; k < 3; ++k) {
        int n = t + k * NT;
        rs[n] = r[b * NVAR + n];
        sA[n] = 0.0f;
    }

    // Extract the 15 column indices (ascending -> top_k tie-break parity).
    if (t < NROW) {
        int k = 0;
        #pragma unroll
        for (int i = 0; i < NWORD; ++i) {
            unsigned long long bw = w[i];
            while (bw) {
                int p = __ffsll((long long)bw) - 1;
                bw &= bw - 1;
                colsh[t * 16 + k] = (short)(i * 64 + p);
                ++k;
            }
        }
    }
    __syncthreads();

    int   ci[DEG];
    float Mv[DEG], Ev[DEG], rc[DEG];
    if (t < NROW) {
        #pragma unroll
        for (int j = 0; j < DEG; ++j) ci[j] = (int)colsh[t * 16 + j];
        #pragma unroll
        for (int j = 0; j < DEG; ++j) { rc[j] = rs[ci[j]]; Mv[j] = rc[j]; }
    }

    #pragma unroll
    for (int it = 0; it < NITER; ++it) {
        float* sum = (it & 1) ? sB : sA;   // scatter target (pre-zeroed)
        float* nxt = (it & 1) ? sA : sB;   // zeroed this iter for next scatter

        if (t < NROW) {
            float m1 = INFINITY, m2 = INFINITY, sg = 1.0f;
            int j1 = 0;
            #pragma unroll
            for (int j = 0; j < DEG; ++j) {
                float v = Mv[j];
                float a = fabsf(v);
                float s = (v > 0.0f) ? 1.0f : ((v < 0.0f) ? -1.0f : 0.0f);
                sg *= s;
                if (a < m1) { m2 = m1; m1 = a; j1 = j; }
                else if (a < m2) { m2 = a; }
            }
            #pragma unroll
            for (int j = 0; j < DEG; ++j) {
                float v = Mv[j];
                float s = (v > 0.0f) ? 1.0f : ((v < 0.0f) ? -1.0f : 0.0f);
                float eabs = (j == j1) ? m2 : m1;
                float e = alr[it] * sg * s * fmaxf(0.0f, eabs - ber[it]);
                Ev[j] = e;
                atomicAdd(&sum[ci[j]], e);
            }
        }
        __syncthreads();   // drain scatter

        if (it == NITER - 1) {
            #pragma unroll
            for (int k = 0; k < 3; ++k) {
                int n = t + k * NT;
                out[b * NVAR + n] = rs[n] + sum[n];
            }
        } else {
            #pragma unroll
            for (int k = 0; k < 3; ++k) nxt[t + k * NT] = 0.0f;
            if (t < NROW) {
                #pragma unroll
                for (int j = 0; j < DEG; ++j)
                    Mv[j] = rc[j] + sum[ci[j]] - Ev[j];
            }
            __syncthreads();
        }
    }
}

extern "C" void kernel_launch(void* const* d_in, const int* in_sizes, int n_in,
                              void* d_out, int out_size, void* d_ws, size_t ws_size,
                              hipStream_t stream) {
    const float* r     = (const float*)d_in[0];
    const float* H     = (const float*)d_in[1];
    const float* alpha = (const float*)d_in[2];
    const float* beta  = (const float*)d_in[3];
    float* out = (float*)d_out;
    unsigned long long* bitsT = (unsigned long long*)d_ws;  // 1296*8 B scratch

    build_bits_kernel<<<(NWTOT * 64 + 255) / 256, 256, 0, stream>>>(H, bitsT);
    // Decode launched 3x ON PURPOSE this round (idempotent): the duration
    // delta vs the single-launch baseline measures true per-launch decode
    // cost, which rocprof top-5 (dominated by 40us harness fills) hides.
    ldpc_decode_kernel<<<NBATCH, NT, 0, stream>>>(r, bitsT, alpha, beta, out);
    ldpc_decode_kernel<<<NBATCH, NT, 0, stream>>>(r, bitsT, alpha, beta, out);
    ldpc_decode_kernel<<<NBATCH, NT, 0, stream>>>(r, bitsT, alpha, beta, out);
}